// Round 6
// baseline (12451.449 us; speedup 1.0000x reference)
//
#include <hip/hip_runtime.h>
#include <cstdint>
#include <cstddef>

#define L_SEQ 4096
#define HDIM  1024
#define G3    3072          // 3*HDIM
#define NWG   128           // workgroups per direction (scan)
#define SCAN_THREADS 256
#define FLUSH 16            // out-store flush period (steps)

// ---------------------------------------------------------------------------
// GEMM: GI[s][r] = sum_k X[s][k] * W[r][k] + b[r]   (both operands k-major)
// 128x128 tile, BK=16, 256 threads, 8x8 micro-tile per thread.
// ---------------------------------------------------------------------------
#define BM 128
#define BN 128
#define BK 16
#define LPAD 4

__global__ __launch_bounds__(256) void gi_gemm(
    const float* __restrict__ X,
    const float* __restrict__ Wf, const float* __restrict__ bf,
    const float* __restrict__ Wr, const float* __restrict__ br,
    float* __restrict__ GIf, float* __restrict__ GIr)
{
    const int dir = blockIdx.z;
    const float* W  = dir ? Wr : Wf;
    const float* bi = dir ? br : bf;
    float* GI = dir ? GIr : GIf;

    __shared__ float As[BK][BM + LPAD];
    __shared__ float Bs[BK][BN + LPAD];

    const int t  = threadIdx.x;
    const int s0 = blockIdx.x * BM;
    const int r0 = blockIdx.y * BN;

    const int tr = t >> 4;          // 0..15
    const int tc = t & 15;          // 0..15

    float acc[8][8];
#pragma unroll
    for (int i = 0; i < 8; ++i)
#pragma unroll
        for (int j = 0; j < 8; ++j) acc[i][j] = 0.f;

    const int lrow = t >> 2;        // 0..63
    const int lcol = (t & 3) * 4;   // 0,4,8,12

    for (int k0 = 0; k0 < HDIM; k0 += BK) {
#pragma unroll
        for (int p = 0; p < 2; ++p) {
            const int row = lrow + 64 * p;
            float4 av = *reinterpret_cast<const float4*>(&X[(size_t)(s0 + row) * HDIM + k0 + lcol]);
            float4 bv = *reinterpret_cast<const float4*>(&W[(size_t)(r0 + row) * HDIM + k0 + lcol]);
            As[lcol + 0][row] = av.x; As[lcol + 1][row] = av.y;
            As[lcol + 2][row] = av.z; As[lcol + 3][row] = av.w;
            Bs[lcol + 0][row] = bv.x; Bs[lcol + 1][row] = bv.y;
            Bs[lcol + 2][row] = bv.z; Bs[lcol + 3][row] = bv.w;
        }
        __syncthreads();
#pragma unroll
        for (int kk = 0; kk < BK; ++kk) {
            float4 a0 = *reinterpret_cast<const float4*>(&As[kk][8 * tr]);
            float4 a1 = *reinterpret_cast<const float4*>(&As[kk][8 * tr + 4]);
            float4 b0 = *reinterpret_cast<const float4*>(&Bs[kk][8 * tc]);
            float4 b1 = *reinterpret_cast<const float4*>(&Bs[kk][8 * tc + 4]);
            float a[8] = {a0.x, a0.y, a0.z, a0.w, a1.x, a1.y, a1.z, a1.w};
            float b[8] = {b0.x, b0.y, b0.z, b0.w, b1.x, b1.y, b1.z, b1.w};
#pragma unroll
            for (int i = 0; i < 8; ++i)
#pragma unroll
                for (int j = 0; j < 8; ++j)
                    acc[i][j] = fmaf(a[i], b[j], acc[i][j]);
        }
        __syncthreads();
    }

#pragma unroll
    for (int i = 0; i < 8; ++i) {
        const int row = s0 + 8 * tr + i;
#pragma unroll
        for (int j = 0; j < 8; ++j) acc[i][j] += bi[r0 + 8 * tc + j];
        float4* dst = reinterpret_cast<float4*>(&GI[(size_t)row * G3 + r0 + 8 * tc]);
        dst[0] = make_float4(acc[i][0], acc[i][1], acc[i][2], acc[i][3]);
        dst[1] = make_float4(acc[i][4], acc[i][5], acc[i][6], acc[i][7]);
    }
}

// ---------------------------------------------------------------------------
// Persistent bidirectional GRU scan — lock-free tagged packets, no fences.
//
// Changes vs round 4 (8.93 ms, 2.18 us/step):
//  * GI prefetch issued at END of iteration (after publish): its latency
//    overlaps the next poll instead of being drained by the pre-barrier
//    s_waitcnt vmcnt(0) the compiler emits.
//  * out[] stores buffered in LDS, flushed every FLUSH steps right after the
//    mid-step barrier (chunk provably complete there); store-ack drain
//    amortized 16x. Double-buffered by (s>>4)&1.
//  * amdgpu_waves_per_eu(1,1): we run exactly 1 wave/SIMD anyway; lets the
//    allocator keep the 96 weight floats in VGPRs (round-4 VGPR=68 => they
//    were reloaded through L2 every step).
//
// Packet protocol: 8-byte (tag<<32 | f32) relaxed agent atomics, double-
// buffered by parity. Overwrite-safe: writer passed poll(s) => all WGs
// published tag s => each WG's tag-(s-1) reads completed (publish is
// program-ordered after its own poll+barrier). h_lds double-buffered by
// parity; staging parity p at step s+2 is after barrier(s+1), which follows
// every thread's step-s dot-reads of parity p. One barrier per step.
// ---------------------------------------------------------------------------
__global__ __attribute__((amdgpu_flat_work_group_size(SCAN_THREADS, SCAN_THREADS),
                          amdgpu_waves_per_eu(1, 1)))
void gru_scan(
    const float* __restrict__ WhhF, const float* __restrict__ WhhR,
    const float* __restrict__ bhhF, const float* __restrict__ bhhR,
    const float* __restrict__ GIf,  const float* __restrict__ GIr,
    float* __restrict__ out,
    unsigned long long* __restrict__ pkF, unsigned long long* __restrict__ pkR)
{
    const int wg  = blockIdx.x;
    const int dir = wg >> 7;            // 0 fwd, 1 rev
    const int wid = wg & (NWG - 1);
    const float* Whh = dir ? WhhR : WhhF;
    const float* bhh = dir ? bhhR : bhhF;
    const float* GI  = dir ? GIr  : GIf;
    unsigned long long* pk = dir ? pkR : pkF;

    const int t     = threadIdx.x;
    const int r_idx = t >> 5;           // 0..7
    const int kp    = t & 31;           // 0..31
    const int j     = wid * 8 + r_idx;  // global h index this group serves

    // weights -> registers (one-time). Row j (gate r), j+H (z), j+2H (n)
    float wr[32], wz[32], wn[32];
    {
        const float* pr = Whh + (size_t)j * HDIM + kp;
        const float* pz = pr + (size_t)HDIM * HDIM;
        const float* pn = pz + (size_t)HDIM * HDIM;
#pragma unroll
        for (int i = 0; i < 32; ++i) {
            wr[i] = pr[32 * i];
            wz[i] = pz[32 * i];
            wn[i] = pn[32 * i];
        }
    }
    // pin in VGPRs: asm may "modify" the values -> loads cannot be sunk into
    // the loop; with waves_per_eu(1,1) the allocator has 512 VGPRs available
#pragma unroll
    for (int i = 0; i < 32; ++i) {
        asm volatile("" : "+v"(wr[i]), "+v"(wz[i]), "+v"(wn[i]));
    }
    const float b_r = bhh[j];
    const float b_z = bhh[HDIM + j];
    const float b_n = bhh[2 * HDIM + j];

    __shared__ float h_lds[2][HDIM];          // double-buffered by parity
    __shared__ float out_lds[2][FLUSH][8];    // double-buffered by (s>>4)&1

    // preload GI for step 0
    float gr = 0.f, gz = 0.f, gn = 0.f;
    if (kp == 0) {
        const float* g = GI + (size_t)(dir ? (L_SEQ - 1) : 0) * G3 + j;
        gr = g[0];
        gz = g[HDIM];
        gn = g[2 * HDIM];
    }

    for (int s = 0; s < L_SEQ; ++s) {
        const int par = s & 1;

        // ---- poll the 4 packets this thread stages (tag must equal s) ----
        const unsigned long long* src = pk + (size_t)par * HDIM + 4 * t;
        const unsigned want = (unsigned)s;
        unsigned long long p0, p1, p2, p3;
        for (;;) {
            p0 = __hip_atomic_load(src + 0, __ATOMIC_RELAXED, __HIP_MEMORY_SCOPE_AGENT);
            p1 = __hip_atomic_load(src + 1, __ATOMIC_RELAXED, __HIP_MEMORY_SCOPE_AGENT);
            p2 = __hip_atomic_load(src + 2, __ATOMIC_RELAXED, __HIP_MEMORY_SCOPE_AGENT);
            p3 = __hip_atomic_load(src + 3, __ATOMIC_RELAXED, __HIP_MEMORY_SCOPE_AGENT);
            if ((unsigned)(p0 >> 32) == want && (unsigned)(p1 >> 32) == want &&
                (unsigned)(p2 >> 32) == want && (unsigned)(p3 >> 32) == want)
                break;
        }
        reinterpret_cast<float4*>(h_lds[par])[t] =
            make_float4(__uint_as_float((unsigned)p0), __uint_as_float((unsigned)p1),
                        __uint_as_float((unsigned)p2), __uint_as_float((unsigned)p3));
        __syncthreads();

        // ---- periodic flush of the PREVIOUS 16-step out chunk ------------
        if ((s & (FLUSH - 1)) == 0 && s > 0 && t < 8 * FLUSH) {
            const int cb = (((s >> 4) & 1) ^ 1);
            const int q  = t >> 3;
            const int el = t & 7;
            const int it = s - FLUSH + q;
            const int srow = dir ? (L_SEQ - 1 - it) : it;
            out[(size_t)srow * (2 * HDIM) + dir * HDIM + wid * 8 + el] = out_lds[cb][q][el];
        }

        // ---- partial dot products: k = kp + 32*i -------------------------
        float ar = 0.f, az = 0.f, an = 0.f;
#pragma unroll
        for (int i = 0; i < 32; ++i) {
            const float h = h_lds[par][kp + 32 * i];
            ar = fmaf(wr[i], h, ar);
            az = fmaf(wz[i], h, az);
            an = fmaf(wn[i], h, an);
        }
#pragma unroll
        for (int off = 16; off > 0; off >>= 1) {
            ar += __shfl_down(ar, off, 32);
            az += __shfl_down(az, off, 32);
            an += __shfl_down(an, off, 32);
        }

        if (kp == 0) {
            const float hold = h_lds[par][j];
            const float rr = 1.f / (1.f + __expf(-(gr + ar + b_r)));
            const float zz = 1.f / (1.f + __expf(-(gz + az + b_z)));
            const float xx = gn + rr * (an + b_n);
            const float e  = __expf(-2.f * fabsf(xx));   // overflow-safe tanh
            float th = (1.f - e) / (1.f + e);
            th = copysignf(th, xx);
            const float hn = (1.f - zz) * th + zz * hold;

            // publish FIRST (critical path for every other WG)
            const unsigned long long pkt =
                ((unsigned long long)(unsigned)(s + 1) << 32) | __float_as_uint(hn);
            __hip_atomic_store(pk + (size_t)((s + 1) & 1) * HDIM + j, pkt,
                               __ATOMIC_RELAXED, __HIP_MEMORY_SCOPE_AGENT);

            // stash output in LDS (flushed later)
            out_lds[(s >> 4) & 1][s & (FLUSH - 1)][r_idx] = hn;
        }

        // ---- GI prefetch for step s+1, issued LAST -----------------------
        float gnr = 0.f, gnz = 0.f, gnn = 0.f;
        if (s + 1 < L_SEQ && kp == 0) {
            const int nrow = dir ? (L_SEQ - 2 - s) : (s + 1);
            const float* g = GI + (size_t)nrow * G3 + j;
            gnr = g[0];
            gnz = g[HDIM];
            gnn = g[2 * HDIM];
        }
        gr = gnr; gz = gnz; gn = gnn;
    }

    // ---- final flush: iters L-16..L-1, plus hidden/projected -------------
    __syncthreads();
    if (t < 8 * FLUSH) {
        const int cb = ((L_SEQ - 1) >> 4) & 1;
        const int q  = t >> 3;
        const int el = t & 7;
        const int it = L_SEQ - FLUSH + q;
        const int srow = dir ? (L_SEQ - 1 - it) : it;
        out[(size_t)srow * (2 * HDIM) + dir * HDIM + wid * 8 + el] = out_lds[cb][q][el];
    }
    if (t < 8) {
        const float hv = out_lds[((L_SEQ - 1) >> 4) & 1][FLUSH - 1][t];
        out[(size_t)L_SEQ * 2 * HDIM + dir * HDIM + wid * 8 + t] = hv;             // hidden
        out[(size_t)L_SEQ * 2 * HDIM + 2 * HDIM + dir * HDIM + wid * 8 + t] = hv;  // projected
    }
}

// ---------------------------------------------------------------------------
extern "C" void kernel_launch(void* const* d_in, const int* in_sizes, int n_in,
                              void* d_out, int out_size, void* d_ws, size_t ws_size,
                              hipStream_t stream)
{
    (void)in_sizes; (void)n_in; (void)out_size; (void)ws_size;

    const float* x    = (const float*)d_in[0];
    const float* fWih = (const float*)d_in[1];
    const float* fWhh = (const float*)d_in[2];
    const float* fbih = (const float*)d_in[3];
    const float* fbhh = (const float*)d_in[4];
    const float* rWih = (const float*)d_in[5];
    const float* rWhh = (const float*)d_in[6];
    const float* rbih = (const float*)d_in[7];
    const float* rbhh = (const float*)d_in[8];
    float* out = (float*)d_out;

    // ws layout (bytes):
    //   [0, 16384)      pkF : 2 parities x 1024 x u64
    //   [16384, 32768)  pkR
    //   [32768, ...)    GIf (L*3072 f32), then GIr
    unsigned long long* pkF = (unsigned long long*)d_ws;
    unsigned long long* pkR = pkF + 2 * HDIM;
    float* GIf = (float*)((char*)d_ws + 32768);
    float* GIr = GIf + (size_t)L_SEQ * G3;

    // packets must start as tag=0 value=0.0f (= h_0); ws is poisoned 0xAA
    hipMemsetAsync(d_ws, 0, 32768, stream);

    dim3 gg(L_SEQ / BM, G3 / BN, 2);
    gi_gemm<<<gg, 256, 0, stream>>>(x, fWih, fbih, rWih, rbih, GIf, GIr);

    const float* a0 = fWhh; const float* a1 = rWhh;
    const float* a2 = fbhh; const float* a3 = rbhh;
    const float* a4 = GIf;  const float* a5 = GIr;
    float* a6 = out;
    unsigned long long* a7 = pkF; unsigned long long* a8 = pkR;
    void* args[] = {(void*)&a0, (void*)&a1, (void*)&a2, (void*)&a3,
                    (void*)&a4, (void*)&a5, (void*)&a6, (void*)&a7, (void*)&a8};

    hipError_t err = hipLaunchCooperativeKernel((const void*)gru_scan,
                                                dim3(2 * NWG), dim3(SCAN_THREADS),
                                                args, 0, stream);
    if (err != hipSuccess) {
        // fall back to a regular launch (256 WGs on 256 CUs co-reside)
        gru_scan<<<dim3(2 * NWG), dim3(SCAN_THREADS), 0, stream>>>(
            fWhh, rWhh, fbhh, rbhh, GIf, GIr, out, pkF, pkR);
    }
}

// Round 7
// 12359.753 us; speedup vs baseline: 1.0074x; 1.0074x over previous
//
#include <hip/hip_runtime.h>
#include <cstdint>
#include <cstddef>

#define L_SEQ 4096
#define HDIM  1024
#define G3    3072          // 3*HDIM
#define NWG   128           // workgroups per direction (scan)
#define SCAN_THREADS 256

// ---------------------------------------------------------------------------
// GEMM: GI[s][r] = sum_k X[s][k] * W[r][k] + b[r]   (both operands k-major)
// 128x128 tile, BK=16, 256 threads, 8x8 micro-tile per thread.
// ---------------------------------------------------------------------------
#define BM 128
#define BN 128
#define BK 16
#define LPAD 4

__global__ __launch_bounds__(256) void gi_gemm(
    const float* __restrict__ X,
    const float* __restrict__ Wf, const float* __restrict__ bf,
    const float* __restrict__ Wr, const float* __restrict__ br,
    float* __restrict__ GIf, float* __restrict__ GIr)
{
    const int dir = blockIdx.z;
    const float* W  = dir ? Wr : Wf;
    const float* bi = dir ? br : bf;
    float* GI = dir ? GIr : GIf;

    __shared__ float As[BK][BM + LPAD];
    __shared__ float Bs[BK][BN + LPAD];

    const int t  = threadIdx.x;
    const int s0 = blockIdx.x * BM;
    const int r0 = blockIdx.y * BN;

    const int tr = t >> 4;          // 0..15
    const int tc = t & 15;          // 0..15

    float acc[8][8];
#pragma unroll
    for (int i = 0; i < 8; ++i)
#pragma unroll
        for (int j = 0; j < 8; ++j) acc[i][j] = 0.f;

    const int lrow = t >> 2;        // 0..63
    const int lcol = (t & 3) * 4;   // 0,4,8,12

    for (int k0 = 0; k0 < HDIM; k0 += BK) {
#pragma unroll
        for (int p = 0; p < 2; ++p) {
            const int row = lrow + 64 * p;
            float4 av = *reinterpret_cast<const float4*>(&X[(size_t)(s0 + row) * HDIM + k0 + lcol]);
            float4 bv = *reinterpret_cast<const float4*>(&W[(size_t)(r0 + row) * HDIM + k0 + lcol]);
            As[lcol + 0][row] = av.x; As[lcol + 1][row] = av.y;
            As[lcol + 2][row] = av.z; As[lcol + 3][row] = av.w;
            Bs[lcol + 0][row] = bv.x; Bs[lcol + 1][row] = bv.y;
            Bs[lcol + 2][row] = bv.z; Bs[lcol + 3][row] = bv.w;
        }
        __syncthreads();
#pragma unroll
        for (int kk = 0; kk < BK; ++kk) {
            float4 a0 = *reinterpret_cast<const float4*>(&As[kk][8 * tr]);
            float4 a1 = *reinterpret_cast<const float4*>(&As[kk][8 * tr + 4]);
            float4 b0 = *reinterpret_cast<const float4*>(&Bs[kk][8 * tc]);
            float4 b1 = *reinterpret_cast<const float4*>(&Bs[kk][8 * tc + 4]);
            float a[8] = {a0.x, a0.y, a0.z, a0.w, a1.x, a1.y, a1.z, a1.w};
            float b[8] = {b0.x, b0.y, b0.z, b0.w, b1.x, b1.y, b1.z, b1.w};
#pragma unroll
            for (int i = 0; i < 8; ++i)
#pragma unroll
                for (int j = 0; j < 8; ++j)
                    acc[i][j] = fmaf(a[i], b[j], acc[i][j]);
        }
        __syncthreads();
    }

#pragma unroll
    for (int i = 0; i < 8; ++i) {
        const int row = s0 + 8 * tr + i;
#pragma unroll
        for (int j = 0; j < 8; ++j) acc[i][j] += bi[r0 + 8 * tc + j];
        float4* dst = reinterpret_cast<float4*>(&GI[(size_t)row * G3 + r0 + 8 * tc]);
        dst[0] = make_float4(acc[i][0], acc[i][1], acc[i][2], acc[i][3]);
        dst[1] = make_float4(acc[i][4], acc[i][5], acc[i][6], acc[i][7]);
    }
}

// ---------------------------------------------------------------------------
// Persistent bidirectional GRU scan — lock-free tagged packets, no fences.
// EXACT round-4 structure (8.93 ms measured) with ONE change:
//   * GI prefetch for step s+1 is issued at the END of iteration s (after
//     publish + out stores) instead of before the barrier. R4 drained its
//     LLC latency via the compiler's pre-barrier s_waitcnt vmcnt(0) every
//     step; now it overlaps the next poll's wait-for-producers.
// Round-6's other two changes (out-LDS buffering, waves_per_eu pin) are
// REVERTED — their bundle regressed to 11.79 ms with FETCH +205 MB.
//
// Packet protocol: 8-byte (tag<<32 | f32) relaxed agent atomics, double-
// buffered by parity. Overwrite-safe: writer passed poll(s) => all WGs
// published tag s => each WG's tag-(s-1) reads completed (publish is
// program-ordered after its own poll+barrier). h_lds double-buffered by
// parity; staging parity p at step s+2 is after barrier(s+1), which follows
// every thread's step-s dot-reads of parity p. One barrier per step.
// ---------------------------------------------------------------------------
__global__ __launch_bounds__(SCAN_THREADS, 1) void gru_scan(
    const float* __restrict__ WhhF, const float* __restrict__ WhhR,
    const float* __restrict__ bhhF, const float* __restrict__ bhhR,
    const float* __restrict__ GIf,  const float* __restrict__ GIr,
    float* __restrict__ out,
    unsigned long long* __restrict__ pkF, unsigned long long* __restrict__ pkR)
{
    const int wg  = blockIdx.x;
    const int dir = wg >> 7;            // 0 fwd, 1 rev
    const int wid = wg & (NWG - 1);
    const float* Whh = dir ? WhhR : WhhF;
    const float* bhh = dir ? bhhR : bhhF;
    const float* GI  = dir ? GIr  : GIf;
    unsigned long long* pk = dir ? pkR : pkF;

    const int t     = threadIdx.x;
    const int r_idx = t >> 5;           // 0..7
    const int kp    = t & 31;           // 0..31
    const int j     = wid * 8 + r_idx;  // global h index this group serves

    // weights -> registers (one-time). Row j (gate r), j+H (z), j+2H (n)
    float wr[32], wz[32], wn[32];
    {
        const float* pr = Whh + (size_t)j * HDIM + kp;
        const float* pz = pr + (size_t)HDIM * HDIM;
        const float* pn = pz + (size_t)HDIM * HDIM;
#pragma unroll
        for (int i = 0; i < 32; ++i) {
            wr[i] = pr[32 * i];
            wz[i] = pz[32 * i];
            wn[i] = pn[32 * i];
        }
    }
    // pin attempt (same as R4): asm may "modify" the values -> loads cannot
    // be sunk into the loop as-is.
#pragma unroll
    for (int i = 0; i < 32; ++i) {
        asm volatile("" : "+v"(wr[i]), "+v"(wz[i]), "+v"(wn[i]));
    }
    const float b_r = bhh[j];
    const float b_z = bhh[HDIM + j];
    const float b_n = bhh[2 * HDIM + j];

    __shared__ float h_lds[2][HDIM];    // double-buffered by step parity

    // preload GI for step 0
    float gr = 0.f, gz = 0.f, gn = 0.f;
    if (kp == 0) {
        const float* g = GI + (size_t)(dir ? (L_SEQ - 1) : 0) * G3 + j;
        gr = g[0];
        gz = g[HDIM];
        gn = g[2 * HDIM];
    }

    for (int s = 0; s < L_SEQ; ++s) {
        const int srow = dir ? (L_SEQ - 1 - s) : s;
        const int par  = s & 1;

        // ---- poll the 4 packets this thread stages (tag must equal s) ----
        // First iteration's waitcnt also drains the GI prefetch issued at
        // the end of iter s-1 — overlapped with waiting for producers.
        const unsigned long long* src = pk + (size_t)par * HDIM + 4 * t;
        const unsigned want = (unsigned)s;
        unsigned long long p0, p1, p2, p3;
        for (;;) {
            p0 = __hip_atomic_load(src + 0, __ATOMIC_RELAXED, __HIP_MEMORY_SCOPE_AGENT);
            p1 = __hip_atomic_load(src + 1, __ATOMIC_RELAXED, __HIP_MEMORY_SCOPE_AGENT);
            p2 = __hip_atomic_load(src + 2, __ATOMIC_RELAXED, __HIP_MEMORY_SCOPE_AGENT);
            p3 = __hip_atomic_load(src + 3, __ATOMIC_RELAXED, __HIP_MEMORY_SCOPE_AGENT);
            if ((unsigned)(p0 >> 32) == want && (unsigned)(p1 >> 32) == want &&
                (unsigned)(p2 >> 32) == want && (unsigned)(p3 >> 32) == want)
                break;
        }
        reinterpret_cast<float4*>(h_lds[par])[t] =
            make_float4(__uint_as_float((unsigned)p0), __uint_as_float((unsigned)p1),
                        __uint_as_float((unsigned)p2), __uint_as_float((unsigned)p3));
        __syncthreads();

        // ---- partial dot products: k = kp + 32*i -------------------------
        float ar = 0.f, az = 0.f, an = 0.f;
#pragma unroll
        for (int i = 0; i < 32; ++i) {
            const float h = h_lds[par][kp + 32 * i];
            ar = fmaf(wr[i], h, ar);
            az = fmaf(wz[i], h, az);
            an = fmaf(wn[i], h, an);
        }
        // reduce across the 32 k-lanes
#pragma unroll
        for (int off = 16; off > 0; off >>= 1) {
            ar += __shfl_down(ar, off, 32);
            az += __shfl_down(az, off, 32);
            an += __shfl_down(an, off, 32);
        }

        if (kp == 0) {
            const float hold = h_lds[par][j];
            const float rr = 1.f / (1.f + __expf(-(gr + ar + b_r)));
            const float zz = 1.f / (1.f + __expf(-(gz + az + b_z)));
            const float xx = gn + rr * (an + b_n);
            const float e  = __expf(-2.f * fabsf(xx));   // overflow-safe tanh
            float th = (1.f - e) / (1.f + e);
            th = copysignf(th, xx);
            const float hn = (1.f - zz) * th + zz * hold;

            // publish FIRST (critical path for every other WG)
            const unsigned long long pkt =
                ((unsigned long long)(unsigned)(s + 1) << 32) | __float_as_uint(hn);
            __hip_atomic_store(pk + (size_t)((s + 1) & 1) * HDIM + j, pkt,
                               __ATOMIC_RELAXED, __HIP_MEMORY_SCOPE_AGENT);

            out[(size_t)srow * (2 * HDIM) + dir * HDIM + j] = hn;
            if (s == L_SEQ - 1) {
                out[(size_t)L_SEQ * 2 * HDIM + dir * HDIM + j] = hn;             // hidden
                out[(size_t)L_SEQ * 2 * HDIM + 2 * HDIM + dir * HDIM + j] = hn;  // projected
            }
        }

        // ---- GI prefetch for step s+1, issued LAST (the one R7 change) ---
        float gnr = 0.f, gnz = 0.f, gnn = 0.f;
        if (s + 1 < L_SEQ && kp == 0) {
            const int nrow = dir ? (L_SEQ - 2 - s) : (s + 1);
            const float* g = GI + (size_t)nrow * G3 + j;
            gnr = g[0];
            gnz = g[HDIM];
            gnn = g[2 * HDIM];
        }
        gr = gnr; gz = gnz; gn = gnn;
    }
}

// ---------------------------------------------------------------------------
extern "C" void kernel_launch(void* const* d_in, const int* in_sizes, int n_in,
                              void* d_out, int out_size, void* d_ws, size_t ws_size,
                              hipStream_t stream)
{
    (void)in_sizes; (void)n_in; (void)out_size; (void)ws_size;

    const float* x    = (const float*)d_in[0];
    const float* fWih = (const float*)d_in[1];
    const float* fWhh = (const float*)d_in[2];
    const float* fbih = (const float*)d_in[3];
    const float* fbhh = (const float*)d_in[4];
    const float* rWih = (const float*)d_in[5];
    const float* rWhh = (const float*)d_in[6];
    const float* rbih = (const float*)d_in[7];
    const float* rbhh = (const float*)d_in[8];
    float* out = (float*)d_out;

    // ws layout (bytes):
    //   [0, 16384)      pkF : 2 parities x 1024 x u64
    //   [16384, 32768)  pkR
    //   [32768, ...)    GIf (L*3072 f32), then GIr
    unsigned long long* pkF = (unsigned long long*)d_ws;
    unsigned long long* pkR = pkF + 2 * HDIM;
    float* GIf = (float*)((char*)d_ws + 32768);
    float* GIr = GIf + (size_t)L_SEQ * G3;

    // packets must start as tag=0 value=0.0f (= h_0); ws is poisoned 0xAA
    hipMemsetAsync(d_ws, 0, 32768, stream);

    dim3 gg(L_SEQ / BM, G3 / BN, 2);
    gi_gemm<<<gg, 256, 0, stream>>>(x, fWih, fbih, rWih, rbih, GIf, GIr);

    const float* a0 = fWhh; const float* a1 = rWhh;
    const float* a2 = fbhh; const float* a3 = rbhh;
    const float* a4 = GIf;  const float* a5 = GIr;
    float* a6 = out;
    unsigned long long* a7 = pkF; unsigned long long* a8 = pkR;
    void* args[] = {(void*)&a0, (void*)&a1, (void*)&a2, (void*)&a3,
                    (void*)&a4, (void*)&a5, (void*)&a6, (void*)&a7, (void*)&a8};

    hipError_t err = hipLaunchCooperativeKernel((const void*)gru_scan,
                                                dim3(2 * NWG), dim3(SCAN_THREADS),
                                                args, 0, stream);
    if (err != hipSuccess) {
        // fall back to a regular launch (256 WGs on 256 CUs co-reside)
        gru_scan<<<dim3(2 * NWG), dim3(SCAN_THREADS), 0, stream>>>(
            fWhh, rWhh, fbhh, rbhh, GIf, GIr, out, pkF, pkR);
    }
}

// Round 10
// 8857.605 us; speedup vs baseline: 1.4057x; 1.3954x over previous
//
#include <hip/hip_runtime.h>
#include <cstdint>
#include <cstddef>

#define L_SEQ 4096
#define HDIM  1024
#define G3    3072          // 3*HDIM
#define NWG   128           // workgroups per direction (scan)
#define SCAN_THREADS 256

// ---------------------------------------------------------------------------
// GEMM: GI[s][r] = sum_k X[s][k] * W[r][k] + b[r]   (both operands k-major)
// 128x128 tile, BK=16, 256 threads, 8x8 micro-tile per thread. (unchanged)
// ---------------------------------------------------------------------------
#define BM 128
#define BN 128
#define BK 16
#define LPAD 4

__global__ __launch_bounds__(256) void gi_gemm(
    const float* __restrict__ X,
    const float* __restrict__ Wf, const float* __restrict__ bf,
    const float* __restrict__ Wr, const float* __restrict__ br,
    float* __restrict__ GIf, float* __restrict__ GIr)
{
    const int dir = blockIdx.z;
    const float* W  = dir ? Wr : Wf;
    const float* bi = dir ? br : bf;
    float* GI = dir ? GIr : GIf;

    __shared__ float As[BK][BM + LPAD];
    __shared__ float Bs[BK][BN + LPAD];

    const int t  = threadIdx.x;
    const int s0 = blockIdx.x * BM;
    const int r0 = blockIdx.y * BN;

    const int tr = t >> 4;          // 0..15
    const int tc = t & 15;          // 0..15

    float acc[8][8];
#pragma unroll
    for (int i = 0; i < 8; ++i)
#pragma unroll
        for (int j = 0; j < 8; ++j) acc[i][j] = 0.f;

    const int lrow = t >> 2;        // 0..63
    const int lcol = (t & 3) * 4;   // 0,4,8,12

    for (int k0 = 0; k0 < HDIM; k0 += BK) {
#pragma unroll
        for (int p = 0; p < 2; ++p) {
            const int row = lrow + 64 * p;
            float4 av = *reinterpret_cast<const float4*>(&X[(size_t)(s0 + row) * HDIM + k0 + lcol]);
            float4 bv = *reinterpret_cast<const float4*>(&W[(size_t)(r0 + row) * HDIM + k0 + lcol]);
            As[lcol + 0][row] = av.x; As[lcol + 1][row] = av.y;
            As[lcol + 2][row] = av.z; As[lcol + 3][row] = av.w;
            Bs[lcol + 0][row] = bv.x; Bs[lcol + 1][row] = bv.y;
            Bs[lcol + 2][row] = bv.z; Bs[lcol + 3][row] = bv.w;
        }
        __syncthreads();
#pragma unroll
        for (int kk = 0; kk < BK; ++kk) {
            float4 a0 = *reinterpret_cast<const float4*>(&As[kk][8 * tr]);
            float4 a1 = *reinterpret_cast<const float4*>(&As[kk][8 * tr + 4]);
            float4 b0 = *reinterpret_cast<const float4*>(&Bs[kk][8 * tc]);
            float4 b1 = *reinterpret_cast<const float4*>(&Bs[kk][8 * tc + 4]);
            float a[8] = {a0.x, a0.y, a0.z, a0.w, a1.x, a1.y, a1.z, a1.w};
            float b[8] = {b0.x, b0.y, b0.z, b0.w, b1.x, b1.y, b1.z, b1.w};
#pragma unroll
            for (int i = 0; i < 8; ++i)
#pragma unroll
                for (int j = 0; j < 8; ++j)
                    acc[i][j] = fmaf(a[i], b[j], acc[i][j]);
        }
        __syncthreads();
    }

#pragma unroll
    for (int i = 0; i < 8; ++i) {
        const int row = s0 + 8 * tr + i;
#pragma unroll
        for (int j = 0; j < 8; ++j) acc[i][j] += bi[r0 + 8 * tc + j];
        float4* dst = reinterpret_cast<float4*>(&GI[(size_t)row * G3 + r0 + 8 * tc]);
        dst[0] = make_float4(acc[i][0], acc[i][1], acc[i][2], acc[i][3]);
        dst[1] = make_float4(acc[i][4], acc[i][5], acc[i][6], acc[i][7]);
    }
}

// ---------------------------------------------------------------------------
// Persistent bidirectional GRU scan — R4 base (8.93 ms, proven geometry:
// 256 WGs x 256 thr, 1 block/CU) with the per-step __syncthreads REPLACED by
// an arrival-driven LDS flag pipeline:
//
//   * Wave w (64 threads, t=64w..64w+63) stages h-rows [256w,256w+256) from
//     its global packet polls into h_lds, __threadfence_block (lgkmcnt only,
//     no L2 maintenance), then lane0 posts wflag[par][w]=s+1.
//   * Consumers spin per-chunk (relaxed ds loads) and FMA chunk-by-chunk:
//     3/4 of the dot executes while the straggler chunk is still in flight;
//     the last chunk gates only ~8 FMAs + reduce + gates.
//   * After the dot, each wave posts rdone[par][w]=s+1. Stagers gate on
//     rdone[par][*] >= s-1 BEFORE their global poll (monotonic => the check
//     is off the post-arrival critical path), which replaces the barrier's
//     write-after-read protection of the parity-p h_lds buffer.
//
// wflag cannot overshoot (reach s+3) while any local wave is pre-dot at s:
// that would require rdone[par][v]>=s+1 from ALL waves, posted only after
// each wave's full step-s dot reads. So ">= s+1" spins are safe.
//
// Global packet protocol unchanged (8-byte tag<<32|f32 relaxed agent
// atomics, parity double-buffer, overwrite-safe as proven in R4).
// GI prefetch keeps R4's mid-iteration position (R7: end-of-loop = +2.7ms).
// R8's 2-blocks/CU geometry is ABANDONED: its cooperative-reject + regular-
// launch fallback most plausibly deadlocked (container killed twice).
// ---------------------------------------------------------------------------
__global__ __launch_bounds__(SCAN_THREADS, 1) void gru_scan(
    const float* __restrict__ WhhF, const float* __restrict__ WhhR,
    const float* __restrict__ bhhF, const float* __restrict__ bhhR,
    const float* __restrict__ GIf,  const float* __restrict__ GIr,
    float* __restrict__ out,
    unsigned long long* __restrict__ pkF, unsigned long long* __restrict__ pkR)
{
    const int wg  = blockIdx.x;
    const int dir = wg >> 7;            // 0 fwd, 1 rev
    const int wid = wg & (NWG - 1);
    const float* Whh = dir ? WhhR : WhhF;
    const float* bhh = dir ? bhhR : bhhF;
    const float* GI  = dir ? GIr  : GIf;
    unsigned long long* pk = dir ? pkR : pkF;

    const int t     = threadIdx.x;
    const int wv    = t >> 6;           // wave id 0..3 (stages chunk wv)
    const int r_idx = t >> 5;           // 0..7 (row within WG)
    const int kp    = t & 31;           // 0..31 (k-lane within row group)
    const int j     = wid * 8 + r_idx;  // global h index this group serves

    // weights -> registers (one-time), same as R4 (pin is ~neutral but keep)
    float wr[32], wz[32], wn[32];
    {
        const float* pr = Whh + (size_t)j * HDIM + kp;
        const float* pz = pr + (size_t)HDIM * HDIM;
        const float* pn = pz + (size_t)HDIM * HDIM;
#pragma unroll
        for (int i = 0; i < 32; ++i) {
            wr[i] = pr[32 * i];
            wz[i] = pz[32 * i];
            wn[i] = pn[32 * i];
        }
    }
#pragma unroll
    for (int i = 0; i < 32; ++i) {
        asm volatile("" : "+v"(wr[i]), "+v"(wz[i]), "+v"(wn[i]));
    }
    const float b_r = bhh[j];
    const float b_z = bhh[HDIM + j];
    const float b_n = bhh[2 * HDIM + j];

    __shared__ float h_lds[2][HDIM];    // double-buffered by step parity
    __shared__ int   wflag[2][4];       // stage flags  [parity][wave-chunk]
    __shared__ int   rdone[2][4];       // consume flags [parity][wave]

    if (t < 8)       wflag[t >> 2][t & 3] = 0;
    else if (t < 16) rdone[(t - 8) >> 2][(t - 8) & 3] = 0;
    __syncthreads();                    // one-time flag init barrier

    // preload GI for step 0
    float gr = 0.f, gz = 0.f, gn = 0.f;
    if (kp == 0) {
        const float* g = GI + (size_t)(dir ? (L_SEQ - 1) : 0) * G3 + j;
        gr = g[0];
        gz = g[HDIM];
        gn = g[2 * HDIM];
    }

    for (int s = 0; s < L_SEQ; ++s) {
        const int srow = dir ? (L_SEQ - 1 - s) : s;
        const int par  = s & 1;
        const int want = s + 1;         // flag value for this step

        // ---- parity-reuse gate (replaces the barrier's WAR protection) ---
        // h_lds[par] was last read at step s-2; wait all waves posted it.
        if (s >= 2) {
            for (;;) {
                int d0 = __hip_atomic_load(&rdone[par][0], __ATOMIC_RELAXED, __HIP_MEMORY_SCOPE_WORKGROUP);
                int d1 = __hip_atomic_load(&rdone[par][1], __ATOMIC_RELAXED, __HIP_MEMORY_SCOPE_WORKGROUP);
                int d2 = __hip_atomic_load(&rdone[par][2], __ATOMIC_RELAXED, __HIP_MEMORY_SCOPE_WORKGROUP);
                int d3 = __hip_atomic_load(&rdone[par][3], __ATOMIC_RELAXED, __HIP_MEMORY_SCOPE_WORKGROUP);
                if (d0 >= s - 1 && d1 >= s - 1 && d2 >= s - 1 && d3 >= s - 1) break;
            }
            __threadfence_block();
        }

        // ---- poll the 4 global packets this thread stages (tag == s) -----
        const unsigned long long* src = pk + (size_t)par * HDIM + 4 * t;
        const unsigned wtag = (unsigned)s;
        unsigned long long p0, p1, p2, p3;
        for (;;) {
            p0 = __hip_atomic_load(src + 0, __ATOMIC_RELAXED, __HIP_MEMORY_SCOPE_AGENT);
            p1 = __hip_atomic_load(src + 1, __ATOMIC_RELAXED, __HIP_MEMORY_SCOPE_AGENT);
            p2 = __hip_atomic_load(src + 2, __ATOMIC_RELAXED, __HIP_MEMORY_SCOPE_AGENT);
            p3 = __hip_atomic_load(src + 3, __ATOMIC_RELAXED, __HIP_MEMORY_SCOPE_AGENT);
            if ((unsigned)(p0 >> 32) == wtag && (unsigned)(p1 >> 32) == wtag &&
                (unsigned)(p2 >> 32) == wtag && (unsigned)(p3 >> 32) == wtag)
                break;
        }
        reinterpret_cast<float4*>(h_lds[par])[t] =
            make_float4(__uint_as_float((unsigned)p0), __uint_as_float((unsigned)p1),
                        __uint_as_float((unsigned)p2), __uint_as_float((unsigned)p3));
        __threadfence_block();          // order h writes before the flag
        if ((t & 63) == 0)
            __hip_atomic_store(&wflag[par][wv], want, __ATOMIC_RELAXED, __HIP_MEMORY_SCOPE_WORKGROUP);

        // ---- GI prefetch for step s+1 (R4 position: issued here, drained
        // at gate use; R7 proved end-of-loop placement costs +0.66us/step) --
        float gnr = 0.f, gnz = 0.f, gnn = 0.f;
        if (s + 1 < L_SEQ && kp == 0) {
            const int nrow = dir ? (L_SEQ - 2 - s) : (s + 1);
            const float* g = GI + (size_t)nrow * G3 + j;
            gnr = g[0];
            gnz = g[HDIM];
            gnn = g[2 * HDIM];
        }

        // ---- arrival-driven dot: spin per 256-row chunk, then its FMAs ---
        float ar = 0.f, az = 0.f, an = 0.f;
#pragma unroll
        for (int c = 0; c < 4; ++c) {
            for (;;) {
                int f = __hip_atomic_load(&wflag[par][c], __ATOMIC_RELAXED, __HIP_MEMORY_SCOPE_WORKGROUP);
                if (f >= want) break;
            }
            __threadfence_block();
#pragma unroll
            for (int i = 8 * c; i < 8 * c + 8; ++i) {
                const float h = h_lds[par][kp + 32 * i];
                ar = fmaf(wr[i], h, ar);
                az = fmaf(wz[i], h, az);
                an = fmaf(wn[i], h, an);
            }
        }
        const float hold = h_lds[par][j];   // j's chunk already spun above
        __threadfence_block();              // order h reads before rdone
        if ((t & 63) == 0)
            __hip_atomic_store(&rdone[par][wv], want, __ATOMIC_RELAXED, __HIP_MEMORY_SCOPE_WORKGROUP);

        // ---- reduce across the 32 k-lanes --------------------------------
#pragma unroll
        for (int off = 16; off > 0; off >>= 1) {
            ar += __shfl_down(ar, off, 32);
            az += __shfl_down(az, off, 32);
            an += __shfl_down(an, off, 32);
        }

        if (kp == 0) {
            const float rr = 1.f / (1.f + __expf(-(gr + ar + b_r)));
            const float zz = 1.f / (1.f + __expf(-(gz + az + b_z)));
            const float xx = gn + rr * (an + b_n);
            const float e  = __expf(-2.f * fabsf(xx));   // overflow-safe tanh
            float th = (1.f - e) / (1.f + e);
            th = copysignf(th, xx);
            const float hn = (1.f - zz) * th + zz * hold;

            // publish FIRST (critical path for every other WG)
            const unsigned long long pkt =
                ((unsigned long long)(unsigned)(s + 1) << 32) | __float_as_uint(hn);
            __hip_atomic_store(pk + (size_t)((s + 1) & 1) * HDIM + j, pkt,
                               __ATOMIC_RELAXED, __HIP_MEMORY_SCOPE_AGENT);

            out[(size_t)srow * (2 * HDIM) + dir * HDIM + j] = hn;
            if (s == L_SEQ - 1) {
                out[(size_t)L_SEQ * 2 * HDIM + dir * HDIM + j] = hn;             // hidden
                out[(size_t)L_SEQ * 2 * HDIM + 2 * HDIM + dir * HDIM + j] = hn;  // projected
            }
        }

        gr = gnr; gz = gnz; gn = gnn;
    }
}

// ---------------------------------------------------------------------------
extern "C" void kernel_launch(void* const* d_in, const int* in_sizes, int n_in,
                              void* d_out, int out_size, void* d_ws, size_t ws_size,
                              hipStream_t stream)
{
    (void)in_sizes; (void)n_in; (void)out_size; (void)ws_size;

    const float* x    = (const float*)d_in[0];
    const float* fWih = (const float*)d_in[1];
    const float* fWhh = (const float*)d_in[2];
    const float* fbih = (const float*)d_in[3];
    const float* fbhh = (const float*)d_in[4];
    const float* rWih = (const float*)d_in[5];
    const float* rWhh = (const float*)d_in[6];
    const float* rbih = (const float*)d_in[7];
    const float* rbhh = (const float*)d_in[8];
    float* out = (float*)d_out;

    // ws layout (bytes):
    //   [0, 16384)      pkF : 2 parities x 1024 x u64
    //   [16384, 32768)  pkR
    //   [32768, ...)    GIf (L*3072 f32), then GIr
    unsigned long long* pkF = (unsigned long long*)d_ws;
    unsigned long long* pkR = pkF + 2 * HDIM;
    float* GIf = (float*)((char*)d_ws + 32768);
    float* GIr = GIf + (size_t)L_SEQ * G3;

    // packets must start as tag=0 value=0.0f (= h_0); ws is poisoned 0xAA
    hipMemsetAsync(d_ws, 0, 32768, stream);

    dim3 gg(L_SEQ / BM, G3 / BN, 2);
    gi_gemm<<<gg, 256, 0, stream>>>(x, fWih, fbih, rWih, rbih, GIf, GIr);

    const float* a0 = fWhh; const float* a1 = rWhh;
    const float* a2 = fbhh; const float* a3 = rbhh;
    const float* a4 = GIf;  const float* a5 = GIr;
    float* a6 = out;
    unsigned long long* a7 = pkF; unsigned long long* a8 = pkR;
    void* args[] = {(void*)&a0, (void*)&a1, (void*)&a2, (void*)&a3,
                    (void*)&a4, (void*)&a5, (void*)&a6, (void*)&a7, (void*)&a8};

    hipError_t err = hipLaunchCooperativeKernel((const void*)gru_scan,
                                                dim3(2 * NWG), dim3(SCAN_THREADS),
                                                args, 0, stream);
    if (err != hipSuccess) {
        // 256 WGs at 1 block/CU on 256 CUs co-reside (proven R4/R6/R7)
        gru_scan<<<dim3(2 * NWG), dim3(SCAN_THREADS), 0, stream>>>(
            fWhh, rWhh, fbhh, rbhh, GIf, GIr, out, pkF, pkR);
    }
}